// Round 7
// baseline (116.675 us; speedup 1.0000x reference)
//
#include <hip/hip_runtime.h>
#include <hip/hip_fp16.h>
#include <math.h>
#include <float.h>

#define N_NODES 100000
#define N_EDGES 1200000
#define FEAT 64
#define AVG_D_LOG 2.5649493574615367f  /* log(13.0) */
#define EPS_STD 1e-5f
#define EPS_BN 1e-5
#define AGG_BLOCKS 25000               /* 4 nodes/block, exact: 25000*4 = N_NODES */
#define HN_BLOCKS 6250                 /* N_NODES*FEAT/4/256 */
#define RP_BLOCKS 391                  /* ceil((N_NODES+1)/256) */
#define RED_BLOCKS 256                 /* bn_reduce stage */
#define ROWS_PER_RED 98                /* ceil(25000/256) */
#define OLD_RED_BLOCKS 512             /* fallback path */

typedef _Float16 h2v __attribute__((ext_vector_type(2)));

static __device__ __forceinline__ h2v emax(h2v a, h2v b) {
#if __has_builtin(__builtin_elementwise_max)
    return __builtin_elementwise_max(a, b);
#else
    h2v r; r.x = a.x > b.x ? a.x : b.x; r.y = a.y > b.y ? a.y : b.y; return r;
#endif
}
static __device__ __forceinline__ h2v emin(h2v a, h2v b) {
#if __has_builtin(__builtin_elementwise_min)
    return __builtin_elementwise_min(a, b);
#else
    h2v r; r.x = a.x < b.x ? a.x : b.x; r.y = a.y < b.y ? a.y : b.y; return r;
#endif
}
static __device__ __forceinline__ h2v efma(h2v a, h2v b, h2v c) {
#if __has_builtin(__builtin_elementwise_fma)
    return __builtin_elementwise_fma(a, b, c);
#else
    return a * b + c;
#endif
}
static __device__ __forceinline__ h2v shfl32_h2(h2v v) {
    int i; __builtin_memcpy(&i, &v, 4);
    i = __shfl_xor(i, 32, 64);
    h2v r; __builtin_memcpy(&r, &i, 4);
    return r;
}

// ----------------------------------------------- fused hn(fp16) + rowptr ----
__global__ void __launch_bounds__(256) hn_rowptr(
    const float* __restrict__ h, const float* __restrict__ norm,
    const int* __restrict__ dst,
    __half* __restrict__ hn_h, int* __restrict__ rowptr,
    unsigned* __restrict__ cnt)
{
    const int b = blockIdx.x;
    if (b == 0 && threadIdx.x == 0) *cnt = 0;     // reset last-block counter
    if (b < HN_BLOCKS) {
        const size_t i4 = ((size_t)b * 256 + threadIdx.x) * 4;
        const int node = (int)(i4 >> 6);
        const float nr = norm[node];
        float4 v = *reinterpret_cast<const float4*>(h + i4);
        __half2 p0 = __floats2half2_rn(v.x * nr, v.y * nr);
        __half2 p1 = __floats2half2_rn(v.z * nr, v.w * nr);
        __half2* o = reinterpret_cast<__half2*>(hn_h + i4);
        o[0] = p0; o[1] = p1;
    } else {
        const int n = (b - HN_BLOCKS) * 256 + threadIdx.x;
        if (n > N_NODES) return;
        int lo = 0, hi = N_EDGES;
        while (lo < hi) {
            int mid = (lo + hi) >> 1;
            if (dst[mid] < n) lo = mid + 1; else hi = mid;
        }
        rowptr[n] = lo;
    }
}

// ------------------------------------------------------- aggregation --------
// One wave per node. Lane sub=lane&31 owns features (2sub,2sub+1) as packed
// fp16; half-wave 0 takes even edges, half-wave 1 odd edges; combine via
// shfl_xor(32). Packed accumulate via clang vector ops (v_pk_*_f16).
template <bool WRITE_PSTAT>
__global__ void __launch_bounds__(256) pna_agg3(
    const __half* __restrict__ hn, const float* __restrict__ norm,
    const int* __restrict__ src, const int* __restrict__ rowptr,
    float* __restrict__ out, __half2* __restrict__ pstat)
{
    const int tid    = threadIdx.x;
    const int wid    = tid >> 6;
    const int lane   = tid & 63;
    const int sub    = lane & 31;
    const int halfId = lane >> 5;
    const int node   = blockIdx.x * 4 + wid;           // always < N_NODES

    const int start = __builtin_amdgcn_readfirstlane(rowptr[node]);
    const int end   = __builtin_amdgcn_readfirstlane(rowptr[node + 1]);
    const int deg   = end - start;

    const h2v* __restrict__ hn2 = (const h2v*)hn;      // 32 h2v per node row
    const h2v ownh = hn2[node * 32 + sub];
    const float hnv0 = (float)ownh.x;
    const float hnv1 = (float)ownh.y;

    float v0, v1;
    if (deg > 0) {
        h2v s1 = { (_Float16)0.f, (_Float16)0.f };
        h2v s2 = s1;
        h2v mx = { (_Float16)(-65504.f), (_Float16)(-65504.f) };
        h2v mn = { (_Float16)( 65504.f), (_Float16)( 65504.f) };
        int e = start;
#define ACC(W) do { h2v w_ = (W); s1 += w_; s2 = efma(w_, w_, s2); \
                    mx = emax(mx, w_); mn = emin(mn, w_); } while (0)
        for (; e + 8 <= end; e += 8) {                 // 4 pairs = 8 edges
            const int a0 = src[e + 0], b0 = src[e + 1];
            const int a1 = src[e + 2], b1 = src[e + 3];
            const int a2 = src[e + 4], b2 = src[e + 5];
            const int a3 = src[e + 6], b3 = src[e + 7];
            const int j0 = halfId ? b0 : a0;
            const int j1 = halfId ? b1 : a1;
            const int j2 = halfId ? b2 : a2;
            const int j3 = halfId ? b3 : a3;
            h2v w0 = hn2[j0 * 32 + sub];
            h2v w1 = hn2[j1 * 32 + sub];
            h2v w2 = hn2[j2 * 32 + sub];
            h2v w3 = hn2[j3 * 32 + sub];
            ACC(w0); ACC(w1); ACC(w2); ACC(w3);
        }
        if (e + 4 <= end) {                            // 2 pairs
            const int a0 = src[e + 0], b0 = src[e + 1];
            const int a1 = src[e + 2], b1 = src[e + 3];
            const int j0 = halfId ? b0 : a0;
            const int j1 = halfId ? b1 : a1;
            h2v w0 = hn2[j0 * 32 + sub];
            h2v w1 = hn2[j1 * 32 + sub];
            ACC(w0); ACC(w1);
            e += 4;
        }
        if (e + 2 <= end) {                            // 1 pair
            const int a = src[e], b = src[e + 1];
            const int j = halfId ? b : a;
            h2v w = hn2[j * 32 + sub];
            ACC(w);
            e += 2;
        }
        if (e < end) {                                 // odd last edge: half 0 only
            h2v w = hn2[src[e] * 32 + sub];
            if (halfId == 0) ACC(w);
        }
#undef ACC
        // combine the two half-wave partials (lane <-> lane^32)
        s1 += shfl32_h2(s1);
        s2 += shfl32_h2(s2);
        mx = emax(mx, shfl32_h2(mx));
        mn = emin(mn, shfl32_h2(mn));

        const float invd = 1.0f / (float)deg;
        const float mean0 = (float)s1.x * invd, mean1 = (float)s1.y * invd;
        const float var0 = fmaxf((float)s2.x * invd - mean0 * mean0, 0.f);
        const float var1 = fmaxf((float)s2.y * invd - mean1 * mean1, 0.f);
        const float std0 = sqrtf(var0 + EPS_STD), std1 = sqrtf(var1 + EPS_STD);
        const float logD = logf((float)deg + 1.0f);
        const float nrm  = norm[node];
        const float factor = nrm * (1.0f + logD * (1.0f / AVG_D_LOG) + AVG_D_LOG / logD)
                                 * (1.0f / 13.0f);
        v0 = fmaxf(hnv0 * (1.0f / 13.0f) + (mean0 + (float)mx.x + (float)mn.x + std0) * factor, 0.f);
        v1 = fmaxf(hnv1 * (1.0f / 13.0f) + (mean1 + (float)mx.y + (float)mn.y + std1) * factor, 0.f);
    } else {
        v0 = fmaxf(hnv0 * (1.0f / 13.0f), 0.f);
        v1 = fmaxf(hnv1 * (1.0f / 13.0f), 0.f);
    }

    if (halfId == 0) {
        float2 st; st.x = v0; st.y = v1;
        *reinterpret_cast<float2*>(out + (size_t)node * FEAT + 2 * sub) = st;
    }

    if (WRITE_PSTAT) {
        __shared__ float lsS[4][64];
        __shared__ float lsQ[4][64];
        if (halfId == 0) {
            lsS[wid][2 * sub] = v0; lsS[wid][2 * sub + 1] = v1;
            lsQ[wid][2 * sub] = v0 * v0; lsQ[wid][2 * sub + 1] = v1 * v1;
        }
        __syncthreads();
        if (tid < 64) {
            float S = lsS[0][tid] + lsS[1][tid] + lsS[2][tid] + lsS[3][tid];
            float Q = lsQ[0][tid] + lsQ[1][tid] + lsQ[2][tid] + lsQ[3][tid];
            pstat[(size_t)blockIdx.x * 64 + tid] = __floats2half2_rn(S, Q);
        }
    }
}

// --------------- BN stats: coalesced 2-level reduce in ONE dispatch ---------
// 256 blocks each reduce a contiguous slab of pstat (coalesced); the last
// block to finish (atomic counter) folds the 256 partials -> scale/shift.
// All sums are fixed-order => bit-exact regardless of which block finishes last.
__global__ void __launch_bounds__(256) bn_reduce(
    const __half2* __restrict__ pstat,
    const float* __restrict__ w, const float* __restrict__ b,
    float2* __restrict__ partial, unsigned* __restrict__ cnt,
    float2* __restrict__ ss)
{
    const int tid = threadIdx.x;
    const int f   = tid & 63;
    const int g   = tid >> 6;                          // 0..3
    __shared__ float lS[256], lQ[256];

    const int r0 = (int)blockIdx.x * ROWS_PER_RED;
    const int r1 = min(r0 + ROWS_PER_RED, AGG_BLOCKS);
    float S = 0.f, Q = 0.f;
    for (int r = r0 + g; r < r1; r += 4) {             // coalesced: 64 lanes = 256B row
        __half2 p = pstat[(size_t)r * 64 + f];
        S += __low2float(p); Q += __high2float(p);
    }
    lS[tid] = S; lQ[tid] = Q;
    __syncthreads();
    if (tid < 64) {
        float2 pr;
        pr.x = lS[tid] + lS[tid + 64] + lS[tid + 128] + lS[tid + 192];
        pr.y = lQ[tid] + lQ[tid + 64] + lQ[tid + 128] + lQ[tid + 192];
        partial[(size_t)blockIdx.x * 64 + tid] = pr;
    }
    __threadfence();
    __shared__ unsigned done;
    if (tid == 0) done = atomicAdd(cnt, 1u);
    __syncthreads();
    if (done == RED_BLOCKS - 1) {                      // last block finalizes
        __threadfence();
        float S2 = 0.f, Q2 = 0.f;
        for (int blk = g; blk < RED_BLOCKS; blk += 4) {
            float2 pr = partial[(size_t)blk * 64 + f];
            S2 += pr.x; Q2 += pr.y;
        }
        lS[tid] = S2; lQ[tid] = Q2;
        __syncthreads();
        if (tid < 64) {
            double s = (double)lS[tid] + (double)lS[tid + 64]
                     + (double)lS[tid + 128] + (double)lS[tid + 192];
            double q = (double)lQ[tid] + (double)lQ[tid + 64]
                     + (double)lQ[tid + 128] + (double)lQ[tid + 192];
            double mu   = s / (double)N_NODES;
            double var  = q / (double)N_NODES - mu * mu;
            double rstd = 1.0 / sqrt(var + EPS_BN);
            float sc = (float)rstd * w[tid];
            float2 o; o.x = sc; o.y = b[tid] - (float)mu * sc;
            ss[tid] = o;
        }
    }
}

// -------------------------------------------- fallback BN stats (proven) ----
__global__ void __launch_bounds__(256) bn_partial(
    const float* __restrict__ out1,
    double* __restrict__ psum, double* __restrict__ psumsq)
{
    const int tid = threadIdx.x;
    const int fb  = tid & 15;
    const int grp = tid >> 4;
    double s0 = 0, s1 = 0, s2 = 0, s3 = 0;
    double q0 = 0, q1 = 0, q2 = 0, q3 = 0;
    for (int n = blockIdx.x * 16 + grp; n < N_NODES; n += OLD_RED_BLOCKS * 16) {
        float4 v = *reinterpret_cast<const float4*>(out1 + (size_t)n * FEAT + fb * 4);
        s0 += (double)v.x; q0 += (double)v.x * (double)v.x;
        s1 += (double)v.y; q1 += (double)v.y * (double)v.y;
        s2 += (double)v.z; q2 += (double)v.z * (double)v.z;
        s3 += (double)v.w; q3 += (double)v.w * (double)v.w;
    }
    __shared__ double ls[256 * 4];
    __shared__ double lq[256 * 4];
    ls[tid * 4 + 0] = s0; ls[tid * 4 + 1] = s1; ls[tid * 4 + 2] = s2; ls[tid * 4 + 3] = s3;
    lq[tid * 4 + 0] = q0; lq[tid * 4 + 1] = q1; lq[tid * 4 + 2] = q2; lq[tid * 4 + 3] = q3;
    __syncthreads();
    if (tid < 64) {
        const int f = tid, fblk = f >> 2, j = f & 3;
        double S = 0, Q = 0;
        for (int g = 0; g < 16; ++g) {
            S += ls[(g * 16 + fblk) * 4 + j];
            Q += lq[(g * 16 + fblk) * 4 + j];
        }
        psum  [blockIdx.x * 64 + f] = S;
        psumsq[blockIdx.x * 64 + f] = Q;
    }
}

__global__ void bn_finalize_old(const double* __restrict__ psum,
                                const double* __restrict__ psumsq,
                                const float* __restrict__ w, const float* __restrict__ b,
                                float2* __restrict__ ss)
{
    int f = threadIdx.x;                               // 64 threads
    double s = 0.0, s2 = 0.0;
    for (int blk = 0; blk < OLD_RED_BLOCKS; ++blk) {
        s  += psum  [blk * 64 + f];
        s2 += psumsq[blk * 64 + f];
    }
    double mu   = s / (double)N_NODES;
    double var  = s2 / (double)N_NODES - mu * mu;
    double rstd = 1.0 / sqrt(var + EPS_BN);
    float sc = (float)rstd * w[f];
    float2 o; o.x = sc; o.y = b[f] - (float)mu * sc;
    ss[f] = o;
}

// ------------------------------------------------------- BN apply -----------
__global__ void __launch_bounds__(256) bn_apply2(
    float* __restrict__ out, const float2* __restrict__ ss)
{
    __shared__ float sS[64], sH[64];
    if (threadIdx.x < 64) {
        float2 p = ss[threadIdx.x];
        sS[threadIdx.x] = p.x; sH[threadIdx.x] = p.y;
    }
    __syncthreads();
    const size_t i4 = ((size_t)blockIdx.x * 256 + threadIdx.x) * 4;   // grid exact
    float4 v = *reinterpret_cast<const float4*>(out + i4);
    const int f = (int)(i4 & 63);
    v.x = v.x * sS[f + 0] + sH[f + 0];
    v.y = v.y * sS[f + 1] + sH[f + 1];
    v.z = v.z * sS[f + 2] + sH[f + 2];
    v.w = v.w * sS[f + 3] + sH[f + 3];
    *reinterpret_cast<float4*>(out + i4) = v;
}

// ---------------------------------------------------------------------------
extern "C" void kernel_launch(void* const* d_in, const int* in_sizes, int n_in,
                              void* d_out, int out_size, void* d_ws, size_t ws_size,
                              hipStream_t stream) {
    const float* h    = (const float*)d_in[0];
    const float* norm = (const float*)d_in[1];
    /* d_in[2] = e, unused */
    const float* bnw  = (const float*)d_in[3];
    const float* bnb  = (const float*)d_in[4];
    const int*   src  = (const int*)d_in[5];
    const int*   dst  = (const int*)d_in[6];
    float* out = (float*)d_out;

    char* ws = (char*)d_ws;
    size_t o = 0;
    __half* hnbuf = (__half*)(ws + o);
    o += (((size_t)N_NODES * FEAT * sizeof(__half)) + 255) & ~(size_t)255;    // 12.8 MB
    int* rowptr = (int*)(ws + o);
    o += (((size_t)(N_NODES + 1) * sizeof(int)) + 255) & ~(size_t)255;        // 0.4 MB
    float2* ss = (float2*)(ws + o);      o += 512;
    unsigned* cnt = (unsigned*)(ws + o); o += 256;
    float2* partial = (float2*)(ws + o); o += (size_t)RED_BLOCKS * 64 * sizeof(float2); // 128 KB
    // new path: pstat half2 [AGG_BLOCKS][64]
    __half2* pstat = (__half2*)(ws + o);
    const size_t need_new = o + (size_t)AGG_BLOCKS * 64 * sizeof(__half2);     // +6.4 MB
    // fallback path: psum/psumsq doubles (reuse pstat region)
    double* psum   = (double*)(ws + o);
    double* psumsq = (double*)(ws + o + (size_t)OLD_RED_BLOCKS * 64 * sizeof(double));

    hn_rowptr<<<HN_BLOCKS + RP_BLOCKS, 256, 0, stream>>>(h, norm, dst, hnbuf, rowptr, cnt);

    if (ws_size >= need_new) {
        pna_agg3<true><<<AGG_BLOCKS, 256, 0, stream>>>(hnbuf, norm, src, rowptr, out, pstat);
        bn_reduce<<<RED_BLOCKS, 256, 0, stream>>>(pstat, bnw, bnb, partial, cnt, ss);
    } else {
        pna_agg3<false><<<AGG_BLOCKS, 256, 0, stream>>>(hnbuf, norm, src, rowptr, out, nullptr);
        bn_partial<<<OLD_RED_BLOCKS, 256, 0, stream>>>(out, psum, psumsq);
        bn_finalize_old<<<1, 64, 0, stream>>>(psum, psumsq, bnw, bnb, ss);
    }
    bn_apply2<<<HN_BLOCKS, 256, 0, stream>>>(out, ss);
}

// Round 8
// 103.855 us; speedup vs baseline: 1.1234x; 1.1234x over previous
//
#include <hip/hip_runtime.h>
#include <hip/hip_fp16.h>
#include <math.h>
#include <float.h>

#define N_NODES 100000
#define N_EDGES 1200000
#define FEAT 64
#define AVG_D_LOG 2.5649493574615367f  /* log(13.0) */
#define EPS_STD 1e-5f
#define EPS_BN 1e-5
#define AGG_BLOCKS 12500               /* 2 nodes/wave * 4 waves: 12500*8 = N_NODES */
#define HN_BLOCKS 6250                 /* N_NODES*FEAT/4/256 */
#define RP_BLOCKS 391                  /* ceil((N_NODES+1)/256) */
#define RED_BLOCKS 256                 /* bn_reduce stage */
#define ROWS_PER_RED 49                /* ceil(12500/256) */
#define OLD_RED_BLOCKS 512             /* fallback path */

#if __has_builtin(__builtin_fmaxf16)
#define H16MAX(a,b) __builtin_fmaxf16((a),(b))
#define H16MIN(a,b) __builtin_fminf16((a),(b))
#else
#define H16MAX(a,b) ((a) > (b) ? (a) : (b))
#define H16MIN(a,b) ((a) < (b) ? (a) : (b))
#endif

// ----------------------------------------------- fused hn(fp16) + rowptr ----
__global__ void __launch_bounds__(256) hn_rowptr(
    const float* __restrict__ h, const float* __restrict__ norm,
    const int* __restrict__ dst,
    __half* __restrict__ hn_h, int* __restrict__ rowptr,
    unsigned* __restrict__ cnt)
{
    const int b = blockIdx.x;
    if (b == 0 && threadIdx.x == 0) *cnt = 0;     // reset last-block counter
    if (b < HN_BLOCKS) {
        const size_t i4 = ((size_t)b * 256 + threadIdx.x) * 4;
        const int node = (int)(i4 >> 6);
        const float nr = norm[node];
        float4 v = *reinterpret_cast<const float4*>(h + i4);
        __half2 p0 = __floats2half2_rn(v.x * nr, v.y * nr);
        __half2 p1 = __floats2half2_rn(v.z * nr, v.w * nr);
        __half2* o = reinterpret_cast<__half2*>(hn_h + i4);
        o[0] = p0; o[1] = p1;
    } else {
        const int n = (b - HN_BLOCKS) * 256 + threadIdx.x;
        if (n > N_NODES) return;
        int lo = 0, hi = N_EDGES;
        while (lo < hi) {
            int mid = (lo + hi) >> 1;
            if (dst[mid] < n) lo = mid + 1; else hi = mid;
        }
        rowptr[n] = lo;
    }
}

// ------------------------------------------------------- aggregation --------
// One wave handles TWO consecutive nodes (contiguous edge ranges). Lane =
// feature (fp16 scalar gather, SGPR base + lane offset). Dual batches keep
// 16 gathers in flight. Mixed-precision accumulate (fma_mix), fp16 max/min.
template <bool WRITE_PSTAT>
__global__ void __launch_bounds__(256) pna_agg4(
    const __half* __restrict__ hn, const float* __restrict__ norm,
    const int* __restrict__ src, const int* __restrict__ rowptr,
    float* __restrict__ out, __half2* __restrict__ pstat)
{
    const int tid  = threadIdx.x;
    const int wid  = tid >> 6;
    const int lane = tid & 63;
    const int n0   = (blockIdx.x * 4 + wid) * 2;       // n0, n0+1 < N_NODES

    const int s0 = __builtin_amdgcn_readfirstlane(rowptr[n0]);
    const int e0 = __builtin_amdgcn_readfirstlane(rowptr[n0 + 1]);
    const int e1 = __builtin_amdgcn_readfirstlane(rowptr[n0 + 2]);
    const int degA = e0 - s0;
    const int degB = e1 - e0;

    const _Float16* __restrict__ hnf = (const _Float16*)hn;
    const float ownA = (float)hnf[(size_t)n0 * FEAT + lane];
    const float ownB = (float)hnf[(size_t)(n0 + 1) * FEAT + lane];

    float s1A = 0.f, s2A = 0.f, s1B = 0.f, s2B = 0.f;
    _Float16 mxA = (_Float16)(-65504.f), mnA = (_Float16)(65504.f);
    _Float16 mxB = (_Float16)(-65504.f), mnB = (_Float16)(65504.f);

#define LOADW(J)  (hnf[(size_t)(J) * FEAT + lane])
#define ACCA(W) do { _Float16 w_ = (W); float f_ = (float)w_;                 \
                     s1A = __builtin_fmaf(f_, 1.0f, s1A);                     \
                     s2A = __builtin_fmaf(f_, f_, s2A);                       \
                     mxA = H16MAX(mxA, w_); mnA = H16MIN(mnA, w_); } while (0)
#define ACCB(W) do { _Float16 w_ = (W); float f_ = (float)w_;                 \
                     s1B = __builtin_fmaf(f_, 1.0f, s1B);                     \
                     s2B = __builtin_fmaf(f_, f_, s2B);                       \
                     mxB = H16MAX(mxB, w_); mnB = H16MIN(mnB, w_); } while (0)

    int ea = s0, eb = e0;
    // dual-8: 16 gathers in flight
    while (ea + 8 <= e0 && eb + 8 <= e1) {
        const int a0 = src[ea+0], a1 = src[ea+1], a2 = src[ea+2], a3 = src[ea+3];
        const int a4 = src[ea+4], a5 = src[ea+5], a6 = src[ea+6], a7 = src[ea+7];
        const int b0 = src[eb+0], b1 = src[eb+1], b2 = src[eb+2], b3 = src[eb+3];
        const int b4 = src[eb+4], b5 = src[eb+5], b6 = src[eb+6], b7 = src[eb+7];
        _Float16 wa0 = LOADW(a0), wa1 = LOADW(a1), wa2 = LOADW(a2), wa3 = LOADW(a3);
        _Float16 wa4 = LOADW(a4), wa5 = LOADW(a5), wa6 = LOADW(a6), wa7 = LOADW(a7);
        _Float16 wb0 = LOADW(b0), wb1 = LOADW(b1), wb2 = LOADW(b2), wb3 = LOADW(b3);
        _Float16 wb4 = LOADW(b4), wb5 = LOADW(b5), wb6 = LOADW(b6), wb7 = LOADW(b7);
        ACCA(wa0); ACCA(wa1); ACCA(wa2); ACCA(wa3);
        ACCA(wa4); ACCA(wa5); ACCA(wa6); ACCA(wa7);
        ACCB(wb0); ACCB(wb1); ACCB(wb2); ACCB(wb3);
        ACCB(wb4); ACCB(wb5); ACCB(wb6); ACCB(wb7);
        ea += 8; eb += 8;
    }
    // dual-4
    while (ea + 4 <= e0 && eb + 4 <= e1) {
        const int a0 = src[ea+0], a1 = src[ea+1], a2 = src[ea+2], a3 = src[ea+3];
        const int b0 = src[eb+0], b1 = src[eb+1], b2 = src[eb+2], b3 = src[eb+3];
        _Float16 wa0 = LOADW(a0), wa1 = LOADW(a1), wa2 = LOADW(a2), wa3 = LOADW(a3);
        _Float16 wb0 = LOADW(b0), wb1 = LOADW(b1), wb2 = LOADW(b2), wb3 = LOADW(b3);
        ACCA(wa0); ACCA(wa1); ACCA(wa2); ACCA(wa3);
        ACCB(wb0); ACCB(wb1); ACCB(wb2); ACCB(wb3);
        ea += 4; eb += 4;
    }
    // drain A
    for (; ea + 4 <= e0; ea += 4) {
        const int a0 = src[ea+0], a1 = src[ea+1], a2 = src[ea+2], a3 = src[ea+3];
        _Float16 w0 = LOADW(a0), w1 = LOADW(a1), w2 = LOADW(a2), w3 = LOADW(a3);
        ACCA(w0); ACCA(w1); ACCA(w2); ACCA(w3);
    }
    for (; ea < e0; ++ea) { _Float16 w = LOADW(src[ea]); ACCA(w); }
    // drain B
    for (; eb + 4 <= e1; eb += 4) {
        const int b0 = src[eb+0], b1 = src[eb+1], b2 = src[eb+2], b3 = src[eb+3];
        _Float16 w0 = LOADW(b0), w1 = LOADW(b1), w2 = LOADW(b2), w3 = LOADW(b3);
        ACCB(w0); ACCB(w1); ACCB(w2); ACCB(w3);
    }
    for (; eb < e1; ++eb) { _Float16 w = LOADW(src[eb]); ACCB(w); }
#undef ACCA
#undef ACCB
#undef LOADW

    float vA, vB;
    {
        float pre;
        if (degA > 0) {
            const float invd = 1.0f / (float)degA;
            const float mean = s1A * invd;
            const float var  = fmaxf(s2A * invd - mean * mean, 0.f);
            const float stdv = sqrtf(var + EPS_STD);
            const float logD = logf((float)degA + 1.0f);
            const float factor = norm[n0] * (1.0f + logD * (1.0f / AVG_D_LOG) + AVG_D_LOG / logD)
                                         * (1.0f / 13.0f);
            pre = ownA * (1.0f / 13.0f) + (mean + (float)mxA + (float)mnA + stdv) * factor;
        } else {
            pre = ownA * (1.0f / 13.0f);
        }
        vA = fmaxf(pre, 0.f);
    }
    {
        float pre;
        if (degB > 0) {
            const float invd = 1.0f / (float)degB;
            const float mean = s1B * invd;
            const float var  = fmaxf(s2B * invd - mean * mean, 0.f);
            const float stdv = sqrtf(var + EPS_STD);
            const float logD = logf((float)degB + 1.0f);
            const float factor = norm[n0 + 1] * (1.0f + logD * (1.0f / AVG_D_LOG) + AVG_D_LOG / logD)
                                             * (1.0f / 13.0f);
            pre = ownB * (1.0f / 13.0f) + (mean + (float)mxB + (float)mnB + stdv) * factor;
        } else {
            pre = ownB * (1.0f / 13.0f);
        }
        vB = fmaxf(pre, 0.f);
    }

    out[(size_t)n0 * FEAT + lane]       = vA;
    out[(size_t)(n0 + 1) * FEAT + lane] = vB;

    if (WRITE_PSTAT) {
        __shared__ float lsS[4][64];
        __shared__ float lsQ[4][64];
        lsS[wid][lane] = vA + vB;
        lsQ[wid][lane] = vA * vA + vB * vB;
        __syncthreads();
        if (tid < 64) {
            float S = lsS[0][tid] + lsS[1][tid] + lsS[2][tid] + lsS[3][tid];
            float Q = lsQ[0][tid] + lsQ[1][tid] + lsQ[2][tid] + lsQ[3][tid];
            pstat[(size_t)blockIdx.x * 64 + tid] = __floats2half2_rn(S, Q);
        }
    }
}

// --------------- BN stats: coalesced 2-level reduce in ONE dispatch ---------
__global__ void __launch_bounds__(256) bn_reduce(
    const __half2* __restrict__ pstat,
    const float* __restrict__ w, const float* __restrict__ b,
    float2* __restrict__ partial, unsigned* __restrict__ cnt,
    float2* __restrict__ ss)
{
    const int tid = threadIdx.x;
    const int f   = tid & 63;
    const int g   = tid >> 6;                          // 0..3
    __shared__ float lS[256], lQ[256];

    const int r0 = (int)blockIdx.x * ROWS_PER_RED;
    const int r1 = min(r0 + ROWS_PER_RED, AGG_BLOCKS);
    float S = 0.f, Q = 0.f;
    for (int r = r0 + g; r < r1; r += 4) {             // coalesced 256B rows
        __half2 p = pstat[(size_t)r * 64 + f];
        S += __low2float(p); Q += __high2float(p);
    }
    lS[tid] = S; lQ[tid] = Q;
    __syncthreads();
    if (tid < 64) {
        float2 pr;
        pr.x = lS[tid] + lS[tid + 64] + lS[tid + 128] + lS[tid + 192];
        pr.y = lQ[tid] + lQ[tid + 64] + lQ[tid + 128] + lQ[tid + 192];
        partial[(size_t)blockIdx.x * 64 + tid] = pr;
    }
    __threadfence();
    __shared__ unsigned done;
    if (tid == 0) done = atomicAdd(cnt, 1u);
    __syncthreads();
    if (done == RED_BLOCKS - 1) {                      // last block finalizes
        __threadfence();
        float S2 = 0.f, Q2 = 0.f;
        for (int blk = g; blk < RED_BLOCKS; blk += 4) {
            float2 pr = partial[(size_t)blk * 64 + f];
            S2 += pr.x; Q2 += pr.y;
        }
        lS[tid] = S2; lQ[tid] = Q2;
        __syncthreads();
        if (tid < 64) {
            double s = (double)lS[tid] + (double)lS[tid + 64]
                     + (double)lS[tid + 128] + (double)lS[tid + 192];
            double q = (double)lQ[tid] + (double)lQ[tid + 64]
                     + (double)lQ[tid + 128] + (double)lQ[tid + 192];
            double mu   = s / (double)N_NODES;
            double var  = q / (double)N_NODES - mu * mu;
            double rstd = 1.0 / sqrt(var + EPS_BN);
            float sc = (float)rstd * w[tid];
            float2 o; o.x = sc; o.y = b[tid] - (float)mu * sc;
            ss[tid] = o;
        }
    }
}

// -------------------------------------------- fallback BN stats (proven) ----
__global__ void __launch_bounds__(256) bn_partial(
    const float* __restrict__ out1,
    double* __restrict__ psum, double* __restrict__ psumsq)
{
    const int tid = threadIdx.x;
    const int fb  = tid & 15;
    const int grp = tid >> 4;
    double s0 = 0, s1 = 0, s2 = 0, s3 = 0;
    double q0 = 0, q1 = 0, q2 = 0, q3 = 0;
    for (int n = blockIdx.x * 16 + grp; n < N_NODES; n += OLD_RED_BLOCKS * 16) {
        float4 v = *reinterpret_cast<const float4*>(out1 + (size_t)n * FEAT + fb * 4);
        s0 += (double)v.x; q0 += (double)v.x * (double)v.x;
        s1 += (double)v.y; q1 += (double)v.y * (double)v.y;
        s2 += (double)v.z; q2 += (double)v.z * (double)v.z;
        s3 += (double)v.w; q3 += (double)v.w * (double)v.w;
    }
    __shared__ double ls[256 * 4];
    __shared__ double lq[256 * 4];
    ls[tid * 4 + 0] = s0; ls[tid * 4 + 1] = s1; ls[tid * 4 + 2] = s2; ls[tid * 4 + 3] = s3;
    lq[tid * 4 + 0] = q0; lq[tid * 4 + 1] = q1; lq[tid * 4 + 2] = q2; lq[tid * 4 + 3] = q3;
    __syncthreads();
    if (tid < 64) {
        const int f = tid, fblk = f >> 2, j = f & 3;
        double S = 0, Q = 0;
        for (int g = 0; g < 16; ++g) {
            S += ls[(g * 16 + fblk) * 4 + j];
            Q += lq[(g * 16 + fblk) * 4 + j];
        }
        psum  [blockIdx.x * 64 + f] = S;
        psumsq[blockIdx.x * 64 + f] = Q;
    }
}

__global__ void bn_finalize_old(const double* __restrict__ psum,
                                const double* __restrict__ psumsq,
                                const float* __restrict__ w, const float* __restrict__ b,
                                float2* __restrict__ ss)
{
    int f = threadIdx.x;                               // 64 threads
    double s = 0.0, s2 = 0.0;
    for (int blk = 0; blk < OLD_RED_BLOCKS; ++blk) {
        s  += psum  [blk * 64 + f];
        s2 += psumsq[blk * 64 + f];
    }
    double mu   = s / (double)N_NODES;
    double var  = s2 / (double)N_NODES - mu * mu;
    double rstd = 1.0 / sqrt(var + EPS_BN);
    float sc = (float)rstd * w[f];
    float2 o; o.x = sc; o.y = b[f] - (float)mu * sc;
    ss[f] = o;
}

// ------------------------------------------------------- BN apply -----------
__global__ void __launch_bounds__(256) bn_apply2(
    float* __restrict__ out, const float2* __restrict__ ss)
{
    __shared__ float sS[64], sH[64];
    if (threadIdx.x < 64) {
        float2 p = ss[threadIdx.x];
        sS[threadIdx.x] = p.x; sH[threadIdx.x] = p.y;
    }
    __syncthreads();
    const size_t i4 = ((size_t)blockIdx.x * 256 + threadIdx.x) * 4;   // grid exact
    float4 v = *reinterpret_cast<const float4*>(out + i4);
    const int f = (int)(i4 & 63);
    v.x = v.x * sS[f + 0] + sH[f + 0];
    v.y = v.y * sS[f + 1] + sH[f + 1];
    v.z = v.z * sS[f + 2] + sH[f + 2];
    v.w = v.w * sS[f + 3] + sH[f + 3];
    *reinterpret_cast<float4*>(out + i4) = v;
}

// ---------------------------------------------------------------------------
extern "C" void kernel_launch(void* const* d_in, const int* in_sizes, int n_in,
                              void* d_out, int out_size, void* d_ws, size_t ws_size,
                              hipStream_t stream) {
    const float* h    = (const float*)d_in[0];
    const float* norm = (const float*)d_in[1];
    /* d_in[2] = e, unused */
    const float* bnw  = (const float*)d_in[3];
    const float* bnb  = (const float*)d_in[4];
    const int*   src  = (const int*)d_in[5];
    const int*   dst  = (const int*)d_in[6];
    float* out = (float*)d_out;

    char* ws = (char*)d_ws;
    size_t o = 0;
    __half* hnbuf = (__half*)(ws + o);
    o += (((size_t)N_NODES * FEAT * sizeof(__half)) + 255) & ~(size_t)255;    // 12.8 MB
    int* rowptr = (int*)(ws + o);
    o += (((size_t)(N_NODES + 1) * sizeof(int)) + 255) & ~(size_t)255;        // 0.4 MB
    float2* ss = (float2*)(ws + o);      o += 512;
    unsigned* cnt = (unsigned*)(ws + o); o += 256;
    float2* partial = (float2*)(ws + o); o += (size_t)RED_BLOCKS * 64 * sizeof(float2); // 128 KB
    // new path: pstat half2 [AGG_BLOCKS][64]
    __half2* pstat = (__half2*)(ws + o);
    const size_t need_new = o + (size_t)AGG_BLOCKS * 64 * sizeof(__half2);     // +3.2 MB
    // fallback path: psum/psumsq doubles (reuse pstat region)
    double* psum   = (double*)(ws + o);
    double* psumsq = (double*)(ws + o + (size_t)OLD_RED_BLOCKS * 64 * sizeof(double));

    hn_rowptr<<<HN_BLOCKS + RP_BLOCKS, 256, 0, stream>>>(h, norm, dst, hnbuf, rowptr, cnt);

    if (ws_size >= need_new) {
        pna_agg4<true><<<AGG_BLOCKS, 256, 0, stream>>>(hnbuf, norm, src, rowptr, out, pstat);
        bn_reduce<<<RED_BLOCKS, 256, 0, stream>>>(pstat, bnw, bnb, partial, cnt, ss);
    } else {
        pna_agg4<false><<<AGG_BLOCKS, 256, 0, stream>>>(hnbuf, norm, src, rowptr, out, nullptr);
        bn_partial<<<OLD_RED_BLOCKS, 256, 0, stream>>>(out, psum, psumsq);
        bn_finalize_old<<<1, 64, 0, stream>>>(psum, psumsq, bnw, bnb, ss);
    }
    bn_apply2<<<HN_BLOCKS, 256, 0, stream>>>(out, ss);
}

// Round 9
// 87.858 us; speedup vs baseline: 1.3280x; 1.1821x over previous
//
#include <hip/hip_runtime.h>
#include <hip/hip_fp16.h>
#include <math.h>
#include <float.h>

#define N_NODES 100000
#define N_EDGES 1200000
#define FEAT 64
#define AVG_D_LOG 2.5649493574615367f  /* log(13.0) */
#define EPS_STD 1e-5f
#define EPS_BN 1e-5
#define AGG_BLOCKS 12500               /* 2 nodes/wave * 4 waves: 12500*8 = N_NODES */
#define HN_BLOCKS 6250                 /* N_NODES*FEAT/4/256 */
#define RP_BLOCKS 391                  /* ceil((N_NODES+1)/256) */
#define OLD_RED_BLOCKS 512             /* fallback path */

#if __has_builtin(__builtin_fmaxf16)
#define H16MAX(a,b) __builtin_fmaxf16((a),(b))
#define H16MIN(a,b) __builtin_fminf16((a),(b))
#else
#define H16MAX(a,b) ((a) > (b) ? (a) : (b))
#define H16MIN(a,b) ((a) < (b) ? (a) : (b))
#endif

// ----------------------------------------------- fused hn(fp16) + rowptr ----
__global__ void __launch_bounds__(256) hn_rowptr(
    const float* __restrict__ h, const float* __restrict__ norm,
    const int* __restrict__ dst,
    __half* __restrict__ hn_h, int* __restrict__ rowptr)
{
    const int b = blockIdx.x;
    if (b < HN_BLOCKS) {
        const size_t i4 = ((size_t)b * 256 + threadIdx.x) * 4;
        const int node = (int)(i4 >> 6);
        const float nr = norm[node];
        float4 v = *reinterpret_cast<const float4*>(h + i4);
        __half2 p0 = __floats2half2_rn(v.x * nr, v.y * nr);
        __half2 p1 = __floats2half2_rn(v.z * nr, v.w * nr);
        __half2* o = reinterpret_cast<__half2*>(hn_h + i4);
        o[0] = p0; o[1] = p1;
    } else {
        const int n = (b - HN_BLOCKS) * 256 + threadIdx.x;
        if (n > N_NODES) return;
        int lo = 0, hi = N_EDGES;
        while (lo < hi) {
            int mid = (lo + hi) >> 1;
            if (dst[mid] < n) lo = mid + 1; else hi = mid;
        }
        rowptr[n] = lo;
    }
}

// ------------------------------------------------------- aggregation --------
// One wave handles TWO consecutive nodes (contiguous edge ranges). Lane =
// feature (fp16 scalar gather, SGPR base + lane offset). Dual batches keep
// 16 gathers in flight. Mixed-precision accumulate, fp16 max/min.
// BN partials written TRANSPOSED (pstatS/Q[feature][block]) so the stats
// reduce is coalesced with no inter-block fences.
template <bool WRITE_PSTAT>
__global__ void __launch_bounds__(256) pna_agg5(
    const __half* __restrict__ hn, const float* __restrict__ norm,
    const int* __restrict__ src, const int* __restrict__ rowptr,
    float* __restrict__ out,
    float* __restrict__ pstatS, float* __restrict__ pstatQ)
{
    const int tid  = threadIdx.x;
    const int wid  = tid >> 6;
    const int lane = tid & 63;
    const int n0   = (blockIdx.x * 4 + wid) * 2;       // n0, n0+1 < N_NODES

    const int s0 = __builtin_amdgcn_readfirstlane(rowptr[n0]);
    const int e0 = __builtin_amdgcn_readfirstlane(rowptr[n0 + 1]);
    const int e1 = __builtin_amdgcn_readfirstlane(rowptr[n0 + 2]);
    const int degA = e0 - s0;
    const int degB = e1 - e0;

    const _Float16* __restrict__ hnf = (const _Float16*)hn;
    const float ownA = (float)hnf[(size_t)n0 * FEAT + lane];
    const float ownB = (float)hnf[(size_t)(n0 + 1) * FEAT + lane];

    float s1A = 0.f, s2A = 0.f, s1B = 0.f, s2B = 0.f;
    _Float16 mxA = (_Float16)(-65504.f), mnA = (_Float16)(65504.f);
    _Float16 mxB = (_Float16)(-65504.f), mnB = (_Float16)(65504.f);

#define LOADW(J)  (hnf[(size_t)(J) * FEAT + lane])
#define ACCA(W) do { _Float16 w_ = (W); float f_ = (float)w_;                 \
                     s1A = __builtin_fmaf(f_, 1.0f, s1A);                     \
                     s2A = __builtin_fmaf(f_, f_, s2A);                       \
                     mxA = H16MAX(mxA, w_); mnA = H16MIN(mnA, w_); } while (0)
#define ACCB(W) do { _Float16 w_ = (W); float f_ = (float)w_;                 \
                     s1B = __builtin_fmaf(f_, 1.0f, s1B);                     \
                     s2B = __builtin_fmaf(f_, f_, s2B);                       \
                     mxB = H16MAX(mxB, w_); mnB = H16MIN(mnB, w_); } while (0)

    int ea = s0, eb = e0;
    // dual-8: 16 gathers in flight
    while (ea + 8 <= e0 && eb + 8 <= e1) {
        const int a0 = src[ea+0], a1 = src[ea+1], a2 = src[ea+2], a3 = src[ea+3];
        const int a4 = src[ea+4], a5 = src[ea+5], a6 = src[ea+6], a7 = src[ea+7];
        const int b0 = src[eb+0], b1 = src[eb+1], b2 = src[eb+2], b3 = src[eb+3];
        const int b4 = src[eb+4], b5 = src[eb+5], b6 = src[eb+6], b7 = src[eb+7];
        _Float16 wa0 = LOADW(a0), wa1 = LOADW(a1), wa2 = LOADW(a2), wa3 = LOADW(a3);
        _Float16 wa4 = LOADW(a4), wa5 = LOADW(a5), wa6 = LOADW(a6), wa7 = LOADW(a7);
        _Float16 wb0 = LOADW(b0), wb1 = LOADW(b1), wb2 = LOADW(b2), wb3 = LOADW(b3);
        _Float16 wb4 = LOADW(b4), wb5 = LOADW(b5), wb6 = LOADW(b6), wb7 = LOADW(b7);
        ACCA(wa0); ACCA(wa1); ACCA(wa2); ACCA(wa3);
        ACCA(wa4); ACCA(wa5); ACCA(wa6); ACCA(wa7);
        ACCB(wb0); ACCB(wb1); ACCB(wb2); ACCB(wb3);
        ACCB(wb4); ACCB(wb5); ACCB(wb6); ACCB(wb7);
        ea += 8; eb += 8;
    }
    // dual-4
    while (ea + 4 <= e0 && eb + 4 <= e1) {
        const int a0 = src[ea+0], a1 = src[ea+1], a2 = src[ea+2], a3 = src[ea+3];
        const int b0 = src[eb+0], b1 = src[eb+1], b2 = src[eb+2], b3 = src[eb+3];
        _Float16 wa0 = LOADW(a0), wa1 = LOADW(a1), wa2 = LOADW(a2), wa3 = LOADW(a3);
        _Float16 wb0 = LOADW(b0), wb1 = LOADW(b1), wb2 = LOADW(b2), wb3 = LOADW(b3);
        ACCA(wa0); ACCA(wa1); ACCA(wa2); ACCA(wa3);
        ACCB(wb0); ACCB(wb1); ACCB(wb2); ACCB(wb3);
        ea += 4; eb += 4;
    }
    // drain A
    for (; ea + 4 <= e0; ea += 4) {
        const int a0 = src[ea+0], a1 = src[ea+1], a2 = src[ea+2], a3 = src[ea+3];
        _Float16 w0 = LOADW(a0), w1 = LOADW(a1), w2 = LOADW(a2), w3 = LOADW(a3);
        ACCA(w0); ACCA(w1); ACCA(w2); ACCA(w3);
    }
    for (; ea < e0; ++ea) { _Float16 w = LOADW(src[ea]); ACCA(w); }
    // drain B
    for (; eb + 4 <= e1; eb += 4) {
        const int b0 = src[eb+0], b1 = src[eb+1], b2 = src[eb+2], b3 = src[eb+3];
        _Float16 w0 = LOADW(b0), w1 = LOADW(b1), w2 = LOADW(b2), w3 = LOADW(b3);
        ACCB(w0); ACCB(w1); ACCB(w2); ACCB(w3);
    }
    for (; eb < e1; ++eb) { _Float16 w = LOADW(src[eb]); ACCB(w); }
#undef ACCA
#undef ACCB
#undef LOADW

    float vA, vB;
    {
        float pre;
        if (degA > 0) {
            const float invd = 1.0f / (float)degA;
            const float mean = s1A * invd;
            const float var  = fmaxf(s2A * invd - mean * mean, 0.f);
            const float stdv = sqrtf(var + EPS_STD);
            const float logD = logf((float)degA + 1.0f);
            const float factor = norm[n0] * (1.0f + logD * (1.0f / AVG_D_LOG) + AVG_D_LOG / logD)
                                         * (1.0f / 13.0f);
            pre = ownA * (1.0f / 13.0f) + (mean + (float)mxA + (float)mnA + stdv) * factor;
        } else {
            pre = ownA * (1.0f / 13.0f);
        }
        vA = fmaxf(pre, 0.f);
    }
    {
        float pre;
        if (degB > 0) {
            const float invd = 1.0f / (float)degB;
            const float mean = s1B * invd;
            const float var  = fmaxf(s2B * invd - mean * mean, 0.f);
            const float stdv = sqrtf(var + EPS_STD);
            const float logD = logf((float)degB + 1.0f);
            const float factor = norm[n0 + 1] * (1.0f + logD * (1.0f / AVG_D_LOG) + AVG_D_LOG / logD)
                                             * (1.0f / 13.0f);
            pre = ownB * (1.0f / 13.0f) + (mean + (float)mxB + (float)mnB + stdv) * factor;
        } else {
            pre = ownB * (1.0f / 13.0f);
        }
        vB = fmaxf(pre, 0.f);
    }

    out[(size_t)n0 * FEAT + lane]       = vA;
    out[(size_t)(n0 + 1) * FEAT + lane] = vB;

    if (WRITE_PSTAT) {
        __shared__ float lsS[4][64];
        __shared__ float lsQ[4][64];
        lsS[wid][lane] = vA + vB;
        lsQ[wid][lane] = vA * vA + vB * vB;
        __syncthreads();
        if (tid < 64) {
            float S = lsS[0][tid] + lsS[1][tid] + lsS[2][tid] + lsS[3][tid];
            float Q = lsQ[0][tid] + lsQ[1][tid] + lsQ[2][tid] + lsQ[3][tid];
            // transposed: feature-major so bn_stats reads are contiguous
            pstatS[(size_t)tid * AGG_BLOCKS + blockIdx.x] = S;
            pstatQ[(size_t)tid * AGG_BLOCKS + blockIdx.x] = Q;
        }
    }
}

// ----------------- BN stats: 64 blocks, coalesced, fence-free --------------
__global__ void __launch_bounds__(256) bn_stats(
    const float* __restrict__ pstatS, const float* __restrict__ pstatQ,
    const float* __restrict__ w, const float* __restrict__ b,
    float2* __restrict__ ss)
{
    const int f   = (int)blockIdx.x;                   // 0..63
    const int tid = threadIdx.x;
    const float* Sp = pstatS + (size_t)f * AGG_BLOCKS;
    const float* Qp = pstatQ + (size_t)f * AGG_BLOCKS;
    float S = 0.f, Q = 0.f;
    for (int i = tid; i < AGG_BLOCKS; i += 256) {      // contiguous, coalesced
        S += Sp[i]; Q += Qp[i];
    }
    __shared__ double rs[256], rq[256];
    rs[tid] = (double)S; rq[tid] = (double)Q;
    __syncthreads();
    for (int s = 128; s > 0; s >>= 1) {
        if (tid < s) { rs[tid] += rs[tid + s]; rq[tid] += rq[tid + s]; }
        __syncthreads();
    }
    if (tid == 0) {
        double mu   = rs[0] / (double)N_NODES;
        double var  = rq[0] / (double)N_NODES - mu * mu;
        double rstd = 1.0 / sqrt(var + EPS_BN);
        float sc = (float)rstd * w[f];
        float2 o; o.x = sc; o.y = b[f] - (float)mu * sc;
        ss[f] = o;
    }
}

// -------------------------------------------- fallback BN stats (proven) ----
__global__ void __launch_bounds__(256) bn_partial(
    const float* __restrict__ out1,
    double* __restrict__ psum, double* __restrict__ psumsq)
{
    const int tid = threadIdx.x;
    const int fb  = tid & 15;
    const int grp = tid >> 4;
    double s0 = 0, s1 = 0, s2 = 0, s3 = 0;
    double q0 = 0, q1 = 0, q2 = 0, q3 = 0;
    for (int n = blockIdx.x * 16 + grp; n < N_NODES; n += OLD_RED_BLOCKS * 16) {
        float4 v = *reinterpret_cast<const float4*>(out1 + (size_t)n * FEAT + fb * 4);
        s0 += (double)v.x; q0 += (double)v.x * (double)v.x;
        s1 += (double)v.y; q1 += (double)v.y * (double)v.y;
        s2 += (double)v.z; q2 += (double)v.z * (double)v.z;
        s3 += (double)v.w; q3 += (double)v.w * (double)v.w;
    }
    __shared__ double ls[256 * 4];
    __shared__ double lq[256 * 4];
    ls[tid * 4 + 0] = s0; ls[tid * 4 + 1] = s1; ls[tid * 4 + 2] = s2; ls[tid * 4 + 3] = s3;
    lq[tid * 4 + 0] = q0; lq[tid * 4 + 1] = q1; lq[tid * 4 + 2] = q2; lq[tid * 4 + 3] = q3;
    __syncthreads();
    if (tid < 64) {
        const int f = tid, fblk = f >> 2, j = f & 3;
        double S = 0, Q = 0;
        for (int g = 0; g < 16; ++g) {
            S += ls[(g * 16 + fblk) * 4 + j];
            Q += lq[(g * 16 + fblk) * 4 + j];
        }
        psum  [blockIdx.x * 64 + f] = S;
        psumsq[blockIdx.x * 64 + f] = Q;
    }
}

__global__ void bn_finalize_old(const double* __restrict__ psum,
                                const double* __restrict__ psumsq,
                                const float* __restrict__ w, const float* __restrict__ b,
                                float2* __restrict__ ss)
{
    int f = threadIdx.x;                               // 64 threads
    double s = 0.0, s2 = 0.0;
    for (int blk = 0; blk < OLD_RED_BLOCKS; ++blk) {
        s  += psum  [blk * 64 + f];
        s2 += psumsq[blk * 64 + f];
    }
    double mu   = s / (double)N_NODES;
    double var  = s2 / (double)N_NODES - mu * mu;
    double rstd = 1.0 / sqrt(var + EPS_BN);
    float sc = (float)rstd * w[f];
    float2 o; o.x = sc; o.y = b[f] - (float)mu * sc;
    ss[f] = o;
}

// ------------------------------------------------------- BN apply -----------
__global__ void __launch_bounds__(256) bn_apply2(
    float* __restrict__ out, const float2* __restrict__ ss)
{
    __shared__ float sS[64], sH[64];
    if (threadIdx.x < 64) {
        float2 p = ss[threadIdx.x];
        sS[threadIdx.x] = p.x; sH[threadIdx.x] = p.y;
    }
    __syncthreads();
    const size_t i4 = ((size_t)blockIdx.x * 256 + threadIdx.x) * 4;   // grid exact
    float4 v = *reinterpret_cast<const float4*>(out + i4);
    const int f = (int)(i4 & 63);
    v.x = v.x * sS[f + 0] + sH[f + 0];
    v.y = v.y * sS[f + 1] + sH[f + 1];
    v.z = v.z * sS[f + 2] + sH[f + 2];
    v.w = v.w * sS[f + 3] + sH[f + 3];
    *reinterpret_cast<float4*>(out + i4) = v;
}

// ---------------------------------------------------------------------------
extern "C" void kernel_launch(void* const* d_in, const int* in_sizes, int n_in,
                              void* d_out, int out_size, void* d_ws, size_t ws_size,
                              hipStream_t stream) {
    const float* h    = (const float*)d_in[0];
    const float* norm = (const float*)d_in[1];
    /* d_in[2] = e, unused */
    const float* bnw  = (const float*)d_in[3];
    const float* bnb  = (const float*)d_in[4];
    const int*   src  = (const int*)d_in[5];
    const int*   dst  = (const int*)d_in[6];
    float* out = (float*)d_out;

    char* ws = (char*)d_ws;
    size_t o = 0;
    __half* hnbuf = (__half*)(ws + o);
    o += (((size_t)N_NODES * FEAT * sizeof(__half)) + 255) & ~(size_t)255;    // 12.8 MB
    int* rowptr = (int*)(ws + o);
    o += (((size_t)(N_NODES + 1) * sizeof(int)) + 255) & ~(size_t)255;        // 0.4 MB
    float2* ss = (float2*)(ws + o); o += 512;
    // new path: transposed f32 planes pstatS/Q[64][AGG_BLOCKS]
    float* pstatS = (float*)(ws + o);
    float* pstatQ = (float*)(ws + o + (size_t)64 * AGG_BLOCKS * sizeof(float));
    const size_t need_new = o + 2 * (size_t)64 * AGG_BLOCKS * sizeof(float);   // +6.4 MB
    // fallback path: psum/psumsq doubles (reuse same region)
    double* psum   = (double*)(ws + o);
    double* psumsq = (double*)(ws + o + (size_t)OLD_RED_BLOCKS * 64 * sizeof(double));

    hn_rowptr<<<HN_BLOCKS + RP_BLOCKS, 256, 0, stream>>>(h, norm, dst, hnbuf, rowptr);

    if (ws_size >= need_new) {
        pna_agg5<true><<<AGG_BLOCKS, 256, 0, stream>>>(hnbuf, norm, src, rowptr, out, pstatS, pstatQ);
        bn_stats<<<64, 256, 0, stream>>>(pstatS, pstatQ, bnw, bnb, ss);
    } else {
        pna_agg5<false><<<AGG_BLOCKS, 256, 0, stream>>>(hnbuf, norm, src, rowptr, out, nullptr, nullptr);
        bn_partial<<<OLD_RED_BLOCKS, 256, 0, stream>>>(out, psum, psumsq);
        bn_finalize_old<<<1, 64, 0, stream>>>(psum, psumsq, bnw, bnb, ss);
    }
    bn_apply2<<<HN_BLOCKS, 256, 0, stream>>>(out, ss);
}